// Round 13
// baseline (155.732 us; speedup 1.0000x reference)
//
#include <hip/hip_runtime.h>

#define N_NODES 100000
#define N_EDGES 3200000
#define F_IN 64
#define F_OUT 128

#define BSHIFT 7
#define BKT_NODES 128                                   // nodes per bucket
#define NBKT ((N_NODES + BKT_NODES - 1) / BKT_NODES)    // 782
#define CAP2 4736                                       // mean 4096 + 10 sigma

#define PART_BLOCKS 512
#define PART_THREADS 512
#define CHUNK (N_EDGES / PART_BLOCKS)                   // 6250 exactly
#define PRPT ((CHUNK + PART_THREADS - 1) / PART_THREADS) // 13

#define SORT_THREADS 512
#define RPT 10                                          // ceil(CAP2/512)

__device__ __forceinline__ unsigned short f2bf(float f) {
    unsigned x = __float_as_uint(f);
    return (unsigned short)((x + 0x7FFFu + ((x >> 16) & 1u)) >> 16);   // RNE
}
__device__ __forceinline__ float bf2f(unsigned short h) {
    return __uint_as_float(((unsigned)h) << 16);
}
__device__ __forceinline__ unsigned bf15(float f) {      // w in [0,1): sign bit 0
    unsigned x = __float_as_uint(f);
    return ((x + 0x7FFFu + ((x >> 16) & 1u)) >> 16) & 0x7FFFu;
}

// ---- Phase 1: X->bf16 slice + bucket partition with in-LDS block sort -------
// 512 blocks x 512 thr, 58 KB LDS -> 2 blocks/CU (vs 1 before).
// Emits packed 4B records (src(17b)<<15 | bf16w(15b)) + 1B dstLocal side-array,
// written COALESCED (bucket-sorted in LDS first).
__global__ __launch_bounds__(PART_THREADS) void k_part(const float* __restrict__ X,
                                                       unsigned short* __restrict__ Xh,
                                                       const int* __restrict__ ei,
                                                       const float* __restrict__ ew,
                                                       unsigned* __restrict__ bcur,
                                                       unsigned* __restrict__ pack4,
                                                       unsigned char* __restrict__ dloc8) {
    __shared__ unsigned spack[CHUNK];                    // 25 KB
    __shared__ unsigned short sbkt[CHUNK];               // 12.5 KB
    __shared__ unsigned char  sdl[CHUNK];                // 6.25 KB
    __shared__ unsigned pcnt[NBKT];                      // 3.1 KB
    __shared__ unsigned lstart[NBKT];
    __shared__ unsigned lcur[NBKT];
    __shared__ unsigned rbase[NBKT];
    __shared__ unsigned sscan[PART_THREADS];             // 2 KB
    const int t = threadIdx.x;
    const int e0 = blockIdx.x * CHUNK;

    // phase 0: convert this block's 1/512 slice of X to bf16 (independent work)
    {
        const int per = (N_NODES * F_IN / 4) / PART_BLOCKS;   // 3125 float4s
        const int s0 = blockIdx.x * per;
        for (int i = t; i < per; i += PART_THREADS) {
            float4 v = ((const float4*)X)[s0 + i];
            ushort4 h;
            h.x = f2bf(v.x); h.y = f2bf(v.y); h.z = f2bf(v.z); h.w = f2bf(v.w);
            ((ushort4*)Xh)[s0 + i] = h;
        }
    }

    for (int i = t; i < NBKT; i += PART_THREADS) { pcnt[i] = 0u; lcur[i] = 0u; }
    __syncthreads();

    // pass 1: load edge streams into registers, count buckets
    unsigned rp[PRPT], rm[PRPT];
    #pragma unroll
    for (int j = 0; j < PRPT; ++j) {
        int i = t + j * PART_THREADS;
        if (i < CHUNK) {
            int dst = __builtin_nontemporal_load(&ei[e0 + i]);
            int src = __builtin_nontemporal_load(&ei[N_EDGES + e0 + i]);
            float w = __builtin_nontemporal_load(&ew[e0 + i]);
            rp[j] = ((unsigned)src << 15) | bf15(w);
            unsigned b = (unsigned)dst >> BSHIFT;
            rm[j] = (b << 7) | ((unsigned)dst & (BKT_NODES - 1));
            atomicAdd(&pcnt[b], 1u);
        }
    }
    __syncthreads();

    // scan over 782 bucket counts: thread t owns bins (2t, 2t+1)
    unsigned c0 = (2 * t < NBKT) ? pcnt[2 * t] : 0u;
    unsigned c1 = (2 * t + 1 < NBKT) ? pcnt[2 * t + 1] : 0u;
    unsigned s = c0 + c1;
    sscan[t] = s;
    __syncthreads();
    for (int off = 1; off < PART_THREADS; off <<= 1) {
        unsigned u = (t >= off) ? sscan[t - off] : 0u;
        __syncthreads();
        sscan[t] += u;
        __syncthreads();
    }
    {
        unsigned base = sscan[t] - s;                    // exclusive over thread sums
        if (2 * t < NBKT) {
            lstart[2 * t] = base;
            rbase[2 * t]  = c0 ? atomicAdd(&bcur[2 * t], c0) : 0u;
        }
        if (2 * t + 1 < NBKT) {
            lstart[2 * t + 1] = base + c0;
            rbase[2 * t + 1]  = c1 ? atomicAdd(&bcur[2 * t + 1], c1) : 0u;
        }
    }
    __syncthreads();

    // place records bucket-sorted into LDS
    #pragma unroll
    for (int j = 0; j < PRPT; ++j) {
        int i = t + j * PART_THREADS;
        if (i < CHUNK) {
            unsigned b = rm[j] >> 7;
            unsigned slot = lstart[b] + atomicAdd(&lcur[b], 1u);
            spack[slot] = rp[j];
            sbkt[slot]  = (unsigned short)b;
            sdl[slot]   = (unsigned char)(rm[j] & (BKT_NODES - 1));
        }
    }
    __syncthreads();

    // coalesced write-out: consecutive slots share buckets -> contiguous runs
    for (int i = t; i < CHUNK; i += PART_THREADS) {
        unsigned b = sbkt[i];
        unsigned dest = rbase[b] + ((unsigned)i - lstart[b]);
        if (dest < CAP2) {                               // overflow guard (p ~ 1e-18)
            pack4[(size_t)b * CAP2 + dest] = spack[i];
            dloc8[(size_t)b * CAP2 + dest] = sdl[i];
        }
    }
}

// ---- Phase 2: per-bucket node sort (packed recs, in place) ------------------
__global__ __launch_bounds__(SORT_THREADS) void k_sort(unsigned* __restrict__ pack4,
                                                       const unsigned char* __restrict__ dloc8,
                                                       const unsigned* __restrict__ bcnt,
                                                       unsigned* __restrict__ nbase,
                                                       unsigned* __restrict__ ndeg) {
    __shared__ unsigned srec[CAP2];                      // 18.9 KB
    __shared__ unsigned lcnt[BKT_NODES];
    __shared__ unsigned sincl[BKT_NODES];
    __shared__ unsigned lcur[BKT_NODES];
    const int t = threadIdx.x;
    const int b = blockIdx.x;
    unsigned cnt = bcnt[b];
    if (cnt > CAP2) cnt = CAP2;
    unsigned* run = pack4 + (size_t)b * CAP2;
    const unsigned char* drun = dloc8 + (size_t)b * CAP2;

    if (t < BKT_NODES) { lcnt[t] = 0u; lcur[t] = 0u; }
    __syncthreads();

    unsigned rp[RPT], rd[RPT];
    #pragma unroll
    for (int j = 0; j < RPT; ++j) {
        unsigned i = t + j * SORT_THREADS;
        if (i < cnt) {
            rp[j] = run[i];
            rd[j] = drun[i];
            atomicAdd(&lcnt[rd[j]], 1u);
        }
    }
    __syncthreads();

    if (t < BKT_NODES) sincl[t] = lcnt[t];
    __syncthreads();
    for (int off = 1; off < BKT_NODES; off <<= 1) {
        unsigned u = (t < BKT_NODES && t >= off) ? sincl[t - off] : 0u;
        __syncthreads();
        if (t < BKT_NODES) sincl[t] += u;
        __syncthreads();
    }

    #pragma unroll
    for (int j = 0; j < RPT; ++j) {
        unsigned i = t + j * SORT_THREADS;
        if (i < cnt) {
            unsigned nl = rd[j];
            unsigned slot = sincl[nl] - lcnt[nl] + atomicAdd(&lcur[nl], 1u);
            srec[slot] = rp[j];
        }
    }
    __syncthreads();

    for (unsigned i = t; i < cnt; i += SORT_THREADS) run[i] = srec[i];   // coalesced
    if (t < BKT_NODES) {
        int node = (b << BSHIFT) + t;
        if (node < N_NODES) {
            nbase[node] = (unsigned)b * CAP2 + sincl[t] - lcnt[t];       // uint units
            ndeg[node]  = lcnt[t];
        }
    }
}

// ---- Phase 3: one wave per node; packed recs + readlane; bf16 A out ---------
__global__ __launch_bounds__(256) void k_gather(const unsigned short* __restrict__ Xh,
                                                const unsigned* __restrict__ recs,
                                                const unsigned* __restrict__ nbase,
                                                const unsigned* __restrict__ ndeg,
                                                unsigned short* __restrict__ Ah) {
    const int node = (blockIdx.x * 256 + threadIdx.x) >> 6;   // 25000*4 == N_NODES
    const int lane = threadIdx.x & 63;
    const unsigned i0 = nbase[node];
    const unsigned d  = ndeg[node];

    float acc = 0.f;
    if (d <= 64u) {                                      // wave-uniform branch (~always)
        unsigned p0 = 0u;
        if (lane < (int)d) p0 = recs[i0 + lane];         // one coalesced load
        for (unsigned i = 0; i < d; i += 8) {
            float v[8], w[8];
            #pragma unroll
            for (int q = 0; q < 8; ++q) {
                unsigned pk = (unsigned)__builtin_amdgcn_readlane((int)p0, (int)(i + q));
                w[q] = __uint_as_float((pk & 0x7FFFu) << 16);      // bf16 w: shift only
                v[q] = bf2f(Xh[(size_t)(pk >> 15) * F_IN + lane]);
            }
            #pragma unroll
            for (int q = 0; q < 8; ++q) acc = fmaf(v[q], w[q], acc);
        }
    } else {                                             // rare (P ~ 1e-8 per node)
        for (unsigned i = 0; i < d; ++i) {
            unsigned pk = recs[i0 + i];
            acc = fmaf(bf2f(Xh[(size_t)(pk >> 15) * F_IN + lane]),
                       __uint_as_float((pk & 0x7FFFu) << 16), acc);
        }
    }
    Ah[(size_t)node * F_IN + lane] = f2bf(acc);
}

// ---- Phase 4: projection + bias + ReLU, 16 nodes/block (bf16 A in) ----------
__global__ __launch_bounds__(256) void k_proj(const unsigned short* __restrict__ Ah,
                                              const float* __restrict__ W,
                                              const float* __restrict__ bias,
                                              float* __restrict__ out) {
    __shared__ float arows[16 * F_IN];                   // 4 KB
    const int t = threadIdx.x;
    const int node0 = blockIdx.x * 16;                   // 6250 blocks exactly
    {
        ushort4 h = ((const ushort4*)(Ah + (size_t)node0 * F_IN))[t];   // 256*4 = 1024
        float4 f;
        f.x = bf2f(h.x); f.y = bf2f(h.y); f.z = bf2f(h.z); f.w = bf2f(h.w);
        ((float4*)arows)[t] = f;
    }
    __syncthreads();

    const int f = t & 127;
    const int g = t >> 7;                                // 0..1, 8 nodes each
    float wcol[F_IN];
    #pragma unroll
    for (int k = 0; k < F_IN; ++k) wcol[k] = W[k * F_OUT + f];   // coalesced
    const float bf = bias[f];
    for (int n = g * 8; n < g * 8 + 8; ++n) {
        float acc = bf;
        #pragma unroll
        for (int k4 = 0; k4 < F_IN / 4; ++k4) {
            float4 a4 = *(const float4*)&arows[n * F_IN + k4 * 4];
            acc = fmaf(a4.x, wcol[k4 * 4 + 0], acc);
            acc = fmaf(a4.y, wcol[k4 * 4 + 1], acc);
            acc = fmaf(a4.z, wcol[k4 * 4 + 2], acc);
            acc = fmaf(a4.w, wcol[k4 * 4 + 3], acc);
        }
        out[(size_t)(node0 + n) * F_OUT + f] = fmaxf(acc, 0.f);
    }
}

// ---------------- Fallback (round-1 path) if workspace too small --------------
__global__ __launch_bounds__(256) void gcn_scatter_fb(const float* __restrict__ X,
                                                      const int* __restrict__ ei,
                                                      const float* __restrict__ ew,
                                                      float* __restrict__ A) {
    const int lane = threadIdx.x & 63;
    const int wave = (blockIdx.x * blockDim.x + threadIdx.x) >> 6;
    const int nW = (gridDim.x * blockDim.x) >> 6;
    for (int e = wave; e < N_EDGES; e += nW) {
        const int dst = ei[e];
        const int src = ei[N_EDGES + e];
        atomicAdd(&A[dst * F_IN + lane], X[src * F_IN + lane] * ew[e]);
    }
}
__global__ __launch_bounds__(128) void gcn_proj_fb(const float* __restrict__ A,
                                                   const float* __restrict__ W,
                                                   const float* __restrict__ bias,
                                                   float* __restrict__ out) {
    __shared__ float arow[F_IN];
    const int n = blockIdx.x, f = threadIdx.x;
    if (f < F_IN) arow[f] = A[n * F_IN + f];
    __syncthreads();
    float acc = bias[f];
    #pragma unroll
    for (int k = 0; k < F_IN; ++k) acc = fmaf(arow[k], W[k * F_OUT + f], acc);
    out[n * F_OUT + f] = fmaxf(acc, 0.0f);
}

extern "C" void kernel_launch(void* const* d_in, const int* in_sizes, int n_in,
                              void* d_out, int out_size, void* d_ws, size_t ws_size,
                              hipStream_t stream) {
    const float* X    = (const float*)d_in[0];
    const int*   ei   = (const int*)  d_in[1];
    const float* ew   = (const float*)d_in[2];
    const float* W    = (const float*)d_in[3];
    const float* bias = (const float*)d_in[4];
    float*       out  = (float*)d_out;

    const size_t pack4_bytes = (size_t)NBKT * CAP2 * 4;                    // 14.8 MB
    const size_t xh_bytes    = (size_t)N_NODES * F_IN * 2;                 // 12.8 MB
    const size_t ah_bytes    = (size_t)N_NODES * F_IN * 2;                 // 12.8 MB
    const size_t nbase_bytes = (size_t)N_NODES * 4;
    const size_t ndeg_bytes  = (size_t)N_NODES * 4;
    const size_t dloc_bytes  = (size_t)NBKT * CAP2;                        // 3.7 MB
    const size_t bcnt_bytes  = (size_t)NBKT * 4;
    const size_t need = pack4_bytes + xh_bytes + ah_bytes + nbase_bytes +
                        ndeg_bytes + dloc_bytes + bcnt_bytes;

    if (ws_size >= need) {
        char* p = (char*)d_ws;
        unsigned*       pack4 = (unsigned*)p;       p += pack4_bytes;
        unsigned short* Xh    = (unsigned short*)p; p += xh_bytes;
        unsigned short* Ah    = (unsigned short*)p; p += ah_bytes;
        unsigned*       nbase = (unsigned*)p;       p += nbase_bytes;
        unsigned*       ndeg  = (unsigned*)p;       p += ndeg_bytes;
        unsigned char*  dloc8 = (unsigned char*)p;  p += dloc_bytes;
        unsigned*       bcur  = (unsigned*)p;       p += bcnt_bytes;

        hipMemsetAsync(bcur, 0, bcnt_bytes, stream);
        k_part<<<PART_BLOCKS, PART_THREADS, 0, stream>>>(X, Xh, ei, ew, bcur, pack4, dloc8);
        k_sort<<<NBKT, SORT_THREADS, 0, stream>>>(pack4, dloc8, bcur, nbase, ndeg);
        k_gather<<<N_NODES / 4, 256, 0, stream>>>(Xh, pack4, nbase, ndeg, Ah);
        k_proj<<<N_NODES / 16, 256, 0, stream>>>(Ah, W, bias, out);
    } else {
        float* A = (float*)d_ws;   // 25.6 MB
        hipMemsetAsync(A, 0, (size_t)N_NODES * F_IN * sizeof(float), stream);
        gcn_scatter_fb<<<4096, 256, 0, stream>>>(X, ei, ew, A);
        gcn_proj_fb<<<N_NODES, 128, 0, stream>>>(A, W, bias, out);
    }
}

// Round 14
// 143.844 us; speedup vs baseline: 1.0826x; 1.0826x over previous
//
#include <hip/hip_runtime.h>

#define N_NODES 100000
#define N_EDGES 3200000
#define F_IN 64
#define F_OUT 128

#define BSHIFT 7
#define BKT_NODES 128                                   // nodes per bucket
#define NBKT ((N_NODES + BKT_NODES - 1) / BKT_NODES)    // 782
#define CAP2 4736                                       // mean 4096 + 10 sigma

#define PART_BLOCKS 256
#define PART_THREADS 1024
#define CHUNK (N_EDGES / PART_BLOCKS)                   // 12500 exactly
#define PRPT ((CHUNK + PART_THREADS - 1) / PART_THREADS) // 13

#define SORT_THREADS 512
#define RPT 10                                          // ceil(CAP2/512)

#define XH_BYTES (N_NODES * F_IN * 2)                   // 12.8 MB

typedef __attribute__((__vector_size__(16))) unsigned v4u;

__device__ __forceinline__ unsigned short f2bf(float f) {
    unsigned x = __float_as_uint(f);
    return (unsigned short)((x + 0x7FFFu + ((x >> 16) & 1u)) >> 16);   // RNE
}
__device__ __forceinline__ float bf2f(unsigned short h) {
    return __uint_as_float(((unsigned)h) << 16);
}
__device__ __forceinline__ unsigned bf15(float f) {      // w in [0,1): sign bit 0
    unsigned x = __float_as_uint(f);
    return ((x + 0x7FFFu + ((x >> 16) & 1u)) >> 16) & 0x7FFFu;
}

// ---- Phase 1: X->bf16 slice + bucket partition with in-LDS block sort -------
// (round-12 proven config: 256 blocks x 1024 threads)
__global__ __launch_bounds__(PART_THREADS) void k_part(const float* __restrict__ X,
                                                       unsigned short* __restrict__ Xh,
                                                       const int* __restrict__ ei,
                                                       const float* __restrict__ ew,
                                                       unsigned* __restrict__ bcur,
                                                       unsigned* __restrict__ pack4,
                                                       unsigned char* __restrict__ dloc8) {
    __shared__ unsigned spack[CHUNK];                    // 50 KB
    __shared__ unsigned short sbkt[CHUNK];               // 25 KB
    __shared__ unsigned char  sdl[CHUNK];                // 12.5 KB
    __shared__ unsigned pcnt[NBKT];
    __shared__ unsigned lstart[NBKT];
    __shared__ unsigned lcur[NBKT];
    __shared__ unsigned rbase[NBKT];
    __shared__ unsigned sscan[PART_THREADS];             // 4 KB
    const int t = threadIdx.x;
    const int e0 = blockIdx.x * CHUNK;

    // phase 0: convert this block's 1/256 slice of X to bf16
    {
        const int per = (N_NODES * F_IN / 4) / PART_BLOCKS;   // 6250 float4s
        const int s0 = blockIdx.x * per;
        for (int i = t; i < per; i += PART_THREADS) {
            float4 v = ((const float4*)X)[s0 + i];
            ushort4 h;
            h.x = f2bf(v.x); h.y = f2bf(v.y); h.z = f2bf(v.z); h.w = f2bf(v.w);
            ((ushort4*)Xh)[s0 + i] = h;
        }
    }

    for (int i = t; i < NBKT; i += PART_THREADS) { pcnt[i] = 0u; lcur[i] = 0u; }
    __syncthreads();

    unsigned rp[PRPT], rm[PRPT];
    #pragma unroll
    for (int j = 0; j < PRPT; ++j) {
        int i = t + j * PART_THREADS;
        if (i < CHUNK) {
            int dst = __builtin_nontemporal_load(&ei[e0 + i]);
            int src = __builtin_nontemporal_load(&ei[N_EDGES + e0 + i]);
            float w = __builtin_nontemporal_load(&ew[e0 + i]);
            rp[j] = ((unsigned)src << 15) | bf15(w);
            unsigned b = (unsigned)dst >> BSHIFT;
            rm[j] = (b << 7) | ((unsigned)dst & (BKT_NODES - 1));
            atomicAdd(&pcnt[b], 1u);
        }
    }
    __syncthreads();

    unsigned v = (t < NBKT) ? pcnt[t] : 0u;
    sscan[t] = v;
    __syncthreads();
    for (int off = 1; off < PART_THREADS; off <<= 1) {
        unsigned u = (t >= off) ? sscan[t - off] : 0u;
        __syncthreads();
        sscan[t] += u;
        __syncthreads();
    }
    if (t < NBKT) {
        lstart[t] = sscan[t] - v;
        rbase[t]  = v ? atomicAdd(&bcur[t], v) : 0u;     // bulk reserve
    }
    __syncthreads();

    #pragma unroll
    for (int j = 0; j < PRPT; ++j) {
        int i = t + j * PART_THREADS;
        if (i < CHUNK) {
            unsigned b = rm[j] >> 7;
            unsigned slot = lstart[b] + atomicAdd(&lcur[b], 1u);
            spack[slot] = rp[j];
            sbkt[slot]  = (unsigned short)b;
            sdl[slot]   = (unsigned char)(rm[j] & (BKT_NODES - 1));
        }
    }
    __syncthreads();

    for (int i = t; i < CHUNK; i += PART_THREADS) {
        unsigned b = sbkt[i];
        unsigned dest = rbase[b] + ((unsigned)i - lstart[b]);
        if (dest < CAP2) {                               // overflow guard (p ~ 1e-18)
            pack4[(size_t)b * CAP2 + dest] = spack[i];
            dloc8[(size_t)b * CAP2 + dest] = sdl[i];
        }
    }
}

// ---- Phase 2: per-bucket node sort (packed recs, in place) ------------------
__global__ __launch_bounds__(SORT_THREADS) void k_sort(unsigned* __restrict__ pack4,
                                                       const unsigned char* __restrict__ dloc8,
                                                       const unsigned* __restrict__ bcnt,
                                                       unsigned* __restrict__ nbase,
                                                       unsigned* __restrict__ ndeg) {
    __shared__ unsigned srec[CAP2];                      // 18.9 KB
    __shared__ unsigned lcnt[BKT_NODES];
    __shared__ unsigned sincl[BKT_NODES];
    __shared__ unsigned lcur[BKT_NODES];
    const int t = threadIdx.x;
    const int b = blockIdx.x;
    unsigned cnt = bcnt[b];
    if (cnt > CAP2) cnt = CAP2;
    unsigned* run = pack4 + (size_t)b * CAP2;
    const unsigned char* drun = dloc8 + (size_t)b * CAP2;

    if (t < BKT_NODES) { lcnt[t] = 0u; lcur[t] = 0u; }
    __syncthreads();

    unsigned rp[RPT], rd[RPT];
    #pragma unroll
    for (int j = 0; j < RPT; ++j) {
        unsigned i = t + j * SORT_THREADS;
        if (i < cnt) {
            rp[j] = run[i];
            rd[j] = drun[i];
            atomicAdd(&lcnt[rd[j]], 1u);
        }
    }
    __syncthreads();

    if (t < BKT_NODES) sincl[t] = lcnt[t];
    __syncthreads();
    for (int off = 1; off < BKT_NODES; off <<= 1) {
        unsigned u = (t < BKT_NODES && t >= off) ? sincl[t - off] : 0u;
        __syncthreads();
        if (t < BKT_NODES) sincl[t] += u;
        __syncthreads();
    }

    #pragma unroll
    for (int j = 0; j < RPT; ++j) {
        unsigned i = t + j * SORT_THREADS;
        if (i < cnt) {
            unsigned nl = rd[j];
            unsigned slot = sincl[nl] - lcnt[nl] + atomicAdd(&lcur[nl], 1u);
            srec[slot] = rp[j];
        }
    }
    __syncthreads();

    for (unsigned i = t; i < cnt; i += SORT_THREADS) run[i] = srec[i];   // coalesced
    if (t < BKT_NODES) {
        int node = (b << BSHIFT) + t;
        if (node < N_NODES) {
            nbase[node] = (unsigned)b * CAP2 + sincl[t] - lcnt[t];       // uint units
            ndeg[node]  = lcnt[t];
        }
    }
}

// ---- Phase 3: one wave per node; buffer_load_short_d16_hi + SGPR soffset ----
// Per record: v_readlane + v_fmac only (addr rides in scalar soffset; bf16->f32
// conversion is free via d16_hi into a pre-zeroed VGPR). The 8-load batch and
// its s_waitcnt live in one asm block with tied outputs -> uses are ordered.
__global__ __launch_bounds__(256) void k_gather(const unsigned short* __restrict__ Xh,
                                                const unsigned* __restrict__ recs,
                                                const unsigned* __restrict__ nbase,
                                                const unsigned* __restrict__ ndeg,
                                                unsigned short* __restrict__ Ah) {
    const int node = (blockIdx.x * 256 + threadIdx.x) >> 6;   // 25000*4 == N_NODES
    const int lane = threadIdx.x & 63;
    const unsigned i0 = nbase[node];
    const unsigned d  = ndeg[node];

    v4u rsrc;
    rsrc[0] = (unsigned)(size_t)Xh;
    rsrc[1] = (unsigned)(((size_t)Xh) >> 32);            // stride=0
    rsrc[2] = XH_BYTES;                                  // num_records (bytes)
    rsrc[3] = 0x00020000u;
    const unsigned va = (unsigned)lane * 2u;             // loop-invariant vaddr

    float acc = 0.f;
    if (d <= 64u) {                                      // wave-uniform branch (~always)
        unsigned p0 = 0u;
        if (lane < (int)d) p0 = recs[i0 + lane];         // one coalesced load
        unsigned v0 = 0u, v1 = 0u, v2 = 0u, v3 = 0u, v4 = 0u, v5 = 0u, v6 = 0u, v7 = 0u;
        for (unsigned i = 0; i < d; i += 8) {
            unsigned pk0 = (unsigned)__builtin_amdgcn_readlane((int)p0, (int)(i + 0));
            unsigned pk1 = (unsigned)__builtin_amdgcn_readlane((int)p0, (int)(i + 1));
            unsigned pk2 = (unsigned)__builtin_amdgcn_readlane((int)p0, (int)(i + 2));
            unsigned pk3 = (unsigned)__builtin_amdgcn_readlane((int)p0, (int)(i + 3));
            unsigned pk4 = (unsigned)__builtin_amdgcn_readlane((int)p0, (int)(i + 4));
            unsigned pk5 = (unsigned)__builtin_amdgcn_readlane((int)p0, (int)(i + 5));
            unsigned pk6 = (unsigned)__builtin_amdgcn_readlane((int)p0, (int)(i + 6));
            unsigned pk7 = (unsigned)__builtin_amdgcn_readlane((int)p0, (int)(i + 7));
            asm volatile(
                "buffer_load_short_d16_hi %0, %[va], %[rs], %[o0] offen\n\t"
                "buffer_load_short_d16_hi %1, %[va], %[rs], %[o1] offen\n\t"
                "buffer_load_short_d16_hi %2, %[va], %[rs], %[o2] offen\n\t"
                "buffer_load_short_d16_hi %3, %[va], %[rs], %[o3] offen\n\t"
                "buffer_load_short_d16_hi %4, %[va], %[rs], %[o4] offen\n\t"
                "buffer_load_short_d16_hi %5, %[va], %[rs], %[o5] offen\n\t"
                "buffer_load_short_d16_hi %6, %[va], %[rs], %[o6] offen\n\t"
                "buffer_load_short_d16_hi %7, %[va], %[rs], %[o7] offen\n\t"
                "s_waitcnt vmcnt(0)"
                : "+v"(v0), "+v"(v1), "+v"(v2), "+v"(v3),
                  "+v"(v4), "+v"(v5), "+v"(v6), "+v"(v7)
                : [va]"v"(va), [rs]"s"(rsrc),
                  [o0]"s"((pk0 >> 15) << 7), [o1]"s"((pk1 >> 15) << 7),
                  [o2]"s"((pk2 >> 15) << 7), [o3]"s"((pk3 >> 15) << 7),
                  [o4]"s"((pk4 >> 15) << 7), [o5]"s"((pk5 >> 15) << 7),
                  [o6]"s"((pk6 >> 15) << 7), [o7]"s"((pk7 >> 15) << 7));
            acc = fmaf(__uint_as_float(v0), __uint_as_float((pk0 & 0x7FFFu) << 16), acc);
            acc = fmaf(__uint_as_float(v1), __uint_as_float((pk1 & 0x7FFFu) << 16), acc);
            acc = fmaf(__uint_as_float(v2), __uint_as_float((pk2 & 0x7FFFu) << 16), acc);
            acc = fmaf(__uint_as_float(v3), __uint_as_float((pk3 & 0x7FFFu) << 16), acc);
            acc = fmaf(__uint_as_float(v4), __uint_as_float((pk4 & 0x7FFFu) << 16), acc);
            acc = fmaf(__uint_as_float(v5), __uint_as_float((pk5 & 0x7FFFu) << 16), acc);
            acc = fmaf(__uint_as_float(v6), __uint_as_float((pk6 & 0x7FFFu) << 16), acc);
            acc = fmaf(__uint_as_float(v7), __uint_as_float((pk7 & 0x7FFFu) << 16), acc);
        }
    } else {                                             // rare (P ~ 1e-8 per node)
        for (unsigned i = 0; i < d; ++i) {
            unsigned pk = recs[i0 + i];
            acc = fmaf(bf2f(Xh[(size_t)(pk >> 15) * F_IN + lane]),
                       __uint_as_float((pk & 0x7FFFu) << 16), acc);
        }
    }
    Ah[(size_t)node * F_IN + lane] = f2bf(acc);
}

// ---- Phase 4: projection + bias + ReLU, 16 nodes/block (bf16 A in) ----------
__global__ __launch_bounds__(256) void k_proj(const unsigned short* __restrict__ Ah,
                                              const float* __restrict__ W,
                                              const float* __restrict__ bias,
                                              float* __restrict__ out) {
    __shared__ float arows[16 * F_IN];                   // 4 KB
    const int t = threadIdx.x;
    const int node0 = blockIdx.x * 16;                   // 6250 blocks exactly
    {
        ushort4 h = ((const ushort4*)(Ah + (size_t)node0 * F_IN))[t];   // 256*4 = 1024
        float4 f;
        f.x = bf2f(h.x); f.y = bf2f(h.y); f.z = bf2f(h.z); f.w = bf2f(h.w);
        ((float4*)arows)[t] = f;
    }
    __syncthreads();

    const int f = t & 127;
    const int g = t >> 7;                                // 0..1, 8 nodes each
    float wcol[F_IN];
    #pragma unroll
    for (int k = 0; k < F_IN; ++k) wcol[k] = W[k * F_OUT + f];   // coalesced
    const float bf = bias[f];
    for (int n = g * 8; n < g * 8 + 8; ++n) {
        float acc = bf;
        #pragma unroll
        for (int k4 = 0; k4 < F_IN / 4; ++k4) {
            float4 a4 = *(const float4*)&arows[n * F_IN + k4 * 4];
            acc = fmaf(a4.x, wcol[k4 * 4 + 0], acc);
            acc = fmaf(a4.y, wcol[k4 * 4 + 1], acc);
            acc = fmaf(a4.z, wcol[k4 * 4 + 2], acc);
            acc = fmaf(a4.w, wcol[k4 * 4 + 3], acc);
        }
        out[(size_t)(node0 + n) * F_OUT + f] = fmaxf(acc, 0.f);
    }
}

// ---------------- Fallback (round-1 path) if workspace too small --------------
__global__ __launch_bounds__(256) void gcn_scatter_fb(const float* __restrict__ X,
                                                      const int* __restrict__ ei,
                                                      const float* __restrict__ ew,
                                                      float* __restrict__ A) {
    const int lane = threadIdx.x & 63;
    const int wave = (blockIdx.x * blockDim.x + threadIdx.x) >> 6;
    const int nW = (gridDim.x * blockDim.x) >> 6;
    for (int e = wave; e < N_EDGES; e += nW) {
        const int dst = ei[e];
        const int src = ei[N_EDGES + e];
        atomicAdd(&A[dst * F_IN + lane], X[src * F_IN + lane] * ew[e]);
    }
}
__global__ __launch_bounds__(128) void gcn_proj_fb(const float* __restrict__ A,
                                                   const float* __restrict__ W,
                                                   const float* __restrict__ bias,
                                                   float* __restrict__ out) {
    __shared__ float arow[F_IN];
    const int n = blockIdx.x, f = threadIdx.x;
    if (f < F_IN) arow[f] = A[n * F_IN + f];
    __syncthreads();
    float acc = bias[f];
    #pragma unroll
    for (int k = 0; k < F_IN; ++k) acc = fmaf(arow[k], W[k * F_OUT + f], acc);
    out[n * F_OUT + f] = fmaxf(acc, 0.0f);
}

extern "C" void kernel_launch(void* const* d_in, const int* in_sizes, int n_in,
                              void* d_out, int out_size, void* d_ws, size_t ws_size,
                              hipStream_t stream) {
    const float* X    = (const float*)d_in[0];
    const int*   ei   = (const int*)  d_in[1];
    const float* ew   = (const float*)d_in[2];
    const float* W    = (const float*)d_in[3];
    const float* bias = (const float*)d_in[4];
    float*       out  = (float*)d_out;

    const size_t pack4_bytes = (size_t)NBKT * CAP2 * 4;                    // 14.8 MB
    const size_t xh_bytes    = (size_t)XH_BYTES;                           // 12.8 MB
    const size_t ah_bytes    = (size_t)N_NODES * F_IN * 2;                 // 12.8 MB
    const size_t nbase_bytes = (size_t)N_NODES * 4;
    const size_t ndeg_bytes  = (size_t)N_NODES * 4;
    const size_t dloc_bytes  = (size_t)NBKT * CAP2;                        // 3.7 MB
    const size_t bcnt_bytes  = (size_t)NBKT * 4;
    const size_t need = pack4_bytes + xh_bytes + ah_bytes + nbase_bytes +
                        ndeg_bytes + dloc_bytes + bcnt_bytes;

    if (ws_size >= need) {
        char* p = (char*)d_ws;
        unsigned*       pack4 = (unsigned*)p;       p += pack4_bytes;
        unsigned short* Xh    = (unsigned short*)p; p += xh_bytes;
        unsigned short* Ah    = (unsigned short*)p; p += ah_bytes;
        unsigned*       nbase = (unsigned*)p;       p += nbase_bytes;
        unsigned*       ndeg  = (unsigned*)p;       p += ndeg_bytes;
        unsigned char*  dloc8 = (unsigned char*)p;  p += dloc_bytes;
        unsigned*       bcur  = (unsigned*)p;       p += bcnt_bytes;

        hipMemsetAsync(bcur, 0, bcnt_bytes, stream);
        k_part<<<PART_BLOCKS, PART_THREADS, 0, stream>>>(X, Xh, ei, ew, bcur, pack4, dloc8);
        k_sort<<<NBKT, SORT_THREADS, 0, stream>>>(pack4, dloc8, bcur, nbase, ndeg);
        k_gather<<<N_NODES / 4, 256, 0, stream>>>(Xh, pack4, nbase, ndeg, Ah);
        k_proj<<<N_NODES / 16, 256, 0, stream>>>(Ah, W, bias, out);
    } else {
        float* A = (float*)d_ws;   // 25.6 MB
        hipMemsetAsync(A, 0, (size_t)N_NODES * F_IN * sizeof(float), stream);
        gcn_scatter_fb<<<4096, 256, 0, stream>>>(X, ei, ew, A);
        gcn_proj_fb<<<N_NODES, 128, 0, stream>>>(A, W, bias, out);
    }
}

// Round 15
// 138.399 us; speedup vs baseline: 1.1252x; 1.0393x over previous
//
#include <hip/hip_runtime.h>

#define N_NODES 100000
#define N_EDGES 3200000
#define F_IN 64
#define F_OUT 128

#define BSHIFT 7
#define BKT_NODES 128                                   // nodes per bucket
#define NBKT ((N_NODES + BKT_NODES - 1) / BKT_NODES)    // 782
#define CAP2 4736                                       // mean 4096 + 10 sigma

#define PART_BLOCKS 256
#define PART_THREADS 1024
#define CHUNK (N_EDGES / PART_BLOCKS)                   // 12500 exactly
#define PRPT ((CHUNK + PART_THREADS - 1) / PART_THREADS) // 13

#define SORT_THREADS 512
#define RPT 10                                          // ceil(CAP2/512)

__device__ __forceinline__ unsigned short f2bf(float f) {
    unsigned x = __float_as_uint(f);
    return (unsigned short)((x + 0x7FFFu + ((x >> 16) & 1u)) >> 16);   // RNE
}
__device__ __forceinline__ float bf2f(unsigned short h) {
    return __uint_as_float(((unsigned)h) << 16);
}
__device__ __forceinline__ unsigned bf15(float f) {      // w in [0,1): sign bit 0
    unsigned x = __float_as_uint(f);
    return ((x + 0x7FFFu + ((x >> 16) & 1u)) >> 16) & 0x7FFFu;
}

// ---- Phase 1: X->bf16 slice + bucket partition with in-LDS block sort -------
// (round-12 proven config: 256 blocks x 1024 threads)
__global__ __launch_bounds__(PART_THREADS) void k_part(const float* __restrict__ X,
                                                       unsigned short* __restrict__ Xh,
                                                       const int* __restrict__ ei,
                                                       const float* __restrict__ ew,
                                                       unsigned* __restrict__ bcur,
                                                       unsigned* __restrict__ pack4,
                                                       unsigned char* __restrict__ dloc8) {
    __shared__ unsigned spack[CHUNK];                    // 50 KB
    __shared__ unsigned short sbkt[CHUNK];               // 25 KB
    __shared__ unsigned char  sdl[CHUNK];                // 12.5 KB
    __shared__ unsigned pcnt[NBKT];
    __shared__ unsigned lstart[NBKT];
    __shared__ unsigned lcur[NBKT];
    __shared__ unsigned rbase[NBKT];
    __shared__ unsigned sscan[PART_THREADS];             // 4 KB
    const int t = threadIdx.x;
    const int e0 = blockIdx.x * CHUNK;

    // phase 0: convert this block's 1/256 slice of X to bf16
    {
        const int per = (N_NODES * F_IN / 4) / PART_BLOCKS;   // 6250 float4s
        const int s0 = blockIdx.x * per;
        for (int i = t; i < per; i += PART_THREADS) {
            float4 v = ((const float4*)X)[s0 + i];
            ushort4 h;
            h.x = f2bf(v.x); h.y = f2bf(v.y); h.z = f2bf(v.z); h.w = f2bf(v.w);
            ((ushort4*)Xh)[s0 + i] = h;
        }
    }

    for (int i = t; i < NBKT; i += PART_THREADS) { pcnt[i] = 0u; lcur[i] = 0u; }
    __syncthreads();

    unsigned rp[PRPT], rm[PRPT];
    #pragma unroll
    for (int j = 0; j < PRPT; ++j) {
        int i = t + j * PART_THREADS;
        if (i < CHUNK) {
            int dst = __builtin_nontemporal_load(&ei[e0 + i]);
            int src = __builtin_nontemporal_load(&ei[N_EDGES + e0 + i]);
            float w = __builtin_nontemporal_load(&ew[e0 + i]);
            rp[j] = ((unsigned)src << 15) | bf15(w);
            unsigned b = (unsigned)dst >> BSHIFT;
            rm[j] = (b << 7) | ((unsigned)dst & (BKT_NODES - 1));
            atomicAdd(&pcnt[b], 1u);
        }
    }
    __syncthreads();

    unsigned v = (t < NBKT) ? pcnt[t] : 0u;
    sscan[t] = v;
    __syncthreads();
    for (int off = 1; off < PART_THREADS; off <<= 1) {
        unsigned u = (t >= off) ? sscan[t - off] : 0u;
        __syncthreads();
        sscan[t] += u;
        __syncthreads();
    }
    if (t < NBKT) {
        lstart[t] = sscan[t] - v;
        rbase[t]  = v ? atomicAdd(&bcur[t], v) : 0u;     // bulk reserve
    }
    __syncthreads();

    #pragma unroll
    for (int j = 0; j < PRPT; ++j) {
        int i = t + j * PART_THREADS;
        if (i < CHUNK) {
            unsigned b = rm[j] >> 7;
            unsigned slot = lstart[b] + atomicAdd(&lcur[b], 1u);
            spack[slot] = rp[j];
            sbkt[slot]  = (unsigned short)b;
            sdl[slot]   = (unsigned char)(rm[j] & (BKT_NODES - 1));
        }
    }
    __syncthreads();

    for (int i = t; i < CHUNK; i += PART_THREADS) {
        unsigned b = sbkt[i];
        unsigned dest = rbase[b] + ((unsigned)i - lstart[b]);
        if (dest < CAP2) {                               // overflow guard (p ~ 1e-18)
            pack4[(size_t)b * CAP2 + dest] = spack[i];
            dloc8[(size_t)b * CAP2 + dest] = sdl[i];
        }
    }
}

// ---- Phase 2: per-bucket node sort (packed recs, in place) ------------------
__global__ __launch_bounds__(SORT_THREADS) void k_sort(unsigned* __restrict__ pack4,
                                                       const unsigned char* __restrict__ dloc8,
                                                       const unsigned* __restrict__ bcnt,
                                                       unsigned* __restrict__ nbase,
                                                       unsigned* __restrict__ ndeg) {
    __shared__ unsigned srec[CAP2];                      // 18.9 KB
    __shared__ unsigned lcnt[BKT_NODES];
    __shared__ unsigned sincl[BKT_NODES];
    __shared__ unsigned lcur[BKT_NODES];
    const int t = threadIdx.x;
    const int b = blockIdx.x;
    unsigned cnt = bcnt[b];
    if (cnt > CAP2) cnt = CAP2;
    unsigned* run = pack4 + (size_t)b * CAP2;
    const unsigned char* drun = dloc8 + (size_t)b * CAP2;

    if (t < BKT_NODES) { lcnt[t] = 0u; lcur[t] = 0u; }
    __syncthreads();

    unsigned rp[RPT], rd[RPT];
    #pragma unroll
    for (int j = 0; j < RPT; ++j) {
        unsigned i = t + j * SORT_THREADS;
        if (i < cnt) {
            rp[j] = run[i];
            rd[j] = drun[i];
            atomicAdd(&lcnt[rd[j]], 1u);
        }
    }
    __syncthreads();

    if (t < BKT_NODES) sincl[t] = lcnt[t];
    __syncthreads();
    for (int off = 1; off < BKT_NODES; off <<= 1) {
        unsigned u = (t < BKT_NODES && t >= off) ? sincl[t - off] : 0u;
        __syncthreads();
        if (t < BKT_NODES) sincl[t] += u;
        __syncthreads();
    }

    #pragma unroll
    for (int j = 0; j < RPT; ++j) {
        unsigned i = t + j * SORT_THREADS;
        if (i < cnt) {
            unsigned nl = rd[j];
            unsigned slot = sincl[nl] - lcnt[nl] + atomicAdd(&lcur[nl], 1u);
            srec[slot] = rp[j];
        }
    }
    __syncthreads();

    for (unsigned i = t; i < cnt; i += SORT_THREADS) run[i] = srec[i];   // coalesced
    if (t < BKT_NODES) {
        int node = (b << BSHIFT) + t;
        if (node < N_NODES) {
            nbase[node] = (unsigned)b * CAP2 + sincl[t] - lcnt[t];       // uint units
            ndeg[node]  = lcnt[t];
        }
    }
}

// ---- Phase 3: one wave per node; 16-deep load pipeline ----------------------
// 16 independent bf16-row loads in flight before the first dependent fmac;
// compiler emits staggered vmcnt waits -> latency overlapped across the batch.
// Lanes >= deg hold p0=0 -> sx=0, w=0 -> harmless cached loads (full batches).
__global__ __launch_bounds__(256) void k_gather(const unsigned short* __restrict__ Xh,
                                                const unsigned* __restrict__ recs,
                                                const unsigned* __restrict__ nbase,
                                                const unsigned* __restrict__ ndeg,
                                                unsigned short* __restrict__ Ah) {
    const int node = (blockIdx.x * 256 + threadIdx.x) >> 6;   // 25000*4 == N_NODES
    const int lane = threadIdx.x & 63;
    const unsigned i0 = nbase[node];
    const unsigned d  = ndeg[node];

    float acc = 0.f;
    if (d <= 64u) {                                      // wave-uniform branch (~always)
        unsigned p0 = 0u;
        if (lane < (int)d) p0 = recs[i0 + lane];         // one coalesced load
        for (unsigned i = 0; i < d; i += 16) {
            unsigned pk[16];
            #pragma unroll
            for (int q = 0; q < 16; ++q)
                pk[q] = (unsigned)__builtin_amdgcn_readlane((int)p0, (int)(i + q));
            float v[16];
            #pragma unroll
            for (int q = 0; q < 16; ++q)
                v[q] = bf2f(Xh[(size_t)(pk[q] >> 15) * F_IN + lane]);
            #pragma unroll
            for (int q = 0; q < 16; ++q)
                acc = fmaf(v[q], __uint_as_float((pk[q] & 0x7FFFu) << 16), acc);
        }
    } else {                                             // rare (P ~ 1e-8 per node)
        for (unsigned i = 0; i < d; ++i) {
            unsigned pk = recs[i0 + i];
            acc = fmaf(bf2f(Xh[(size_t)(pk >> 15) * F_IN + lane]),
                       __uint_as_float((pk & 0x7FFFu) << 16), acc);
        }
    }
    Ah[(size_t)node * F_IN + lane] = f2bf(acc);
}

// ---- Phase 4: projection + bias + ReLU, 16 nodes/block (bf16 A in) ----------
__global__ __launch_bounds__(256) void k_proj(const unsigned short* __restrict__ Ah,
                                              const float* __restrict__ W,
                                              const float* __restrict__ bias,
                                              float* __restrict__ out) {
    __shared__ float arows[16 * F_IN];                   // 4 KB
    const int t = threadIdx.x;
    const int node0 = blockIdx.x * 16;                   // 6250 blocks exactly
    {
        ushort4 h = ((const ushort4*)(Ah + (size_t)node0 * F_IN))[t];   // 256*4 = 1024
        float4 f;
        f.x = bf2f(h.x); f.y = bf2f(h.y); f.z = bf2f(h.z); f.w = bf2f(h.w);
        ((float4*)arows)[t] = f;
    }
    __syncthreads();

    const int f = t & 127;
    const int g = t >> 7;                                // 0..1, 8 nodes each
    float wcol[F_IN];
    #pragma unroll
    for (int k = 0; k < F_IN; ++k) wcol[k] = W[k * F_OUT + f];   // coalesced
    const float bf = bias[f];
    for (int n = g * 8; n < g * 8 + 8; ++n) {
        float acc = bf;
        #pragma unroll
        for (int k4 = 0; k4 < F_IN / 4; ++k4) {
            float4 a4 = *(const float4*)&arows[n * F_IN + k4 * 4];
            acc = fmaf(a4.x, wcol[k4 * 4 + 0], acc);
            acc = fmaf(a4.y, wcol[k4 * 4 + 1], acc);
            acc = fmaf(a4.z, wcol[k4 * 4 + 2], acc);
            acc = fmaf(a4.w, wcol[k4 * 4 + 3], acc);
        }
        out[(size_t)(node0 + n) * F_OUT + f] = fmaxf(acc, 0.f);
    }
}

// ---------------- Fallback (round-1 path) if workspace too small --------------
__global__ __launch_bounds__(256) void gcn_scatter_fb(const float* __restrict__ X,
                                                      const int* __restrict__ ei,
                                                      const float* __restrict__ ew,
                                                      float* __restrict__ A) {
    const int lane = threadIdx.x & 63;
    const int wave = (blockIdx.x * blockDim.x + threadIdx.x) >> 6;
    const int nW = (gridDim.x * blockDim.x) >> 6;
    for (int e = wave; e < N_EDGES; e += nW) {
        const int dst = ei[e];
        const int src = ei[N_EDGES + e];
        atomicAdd(&A[dst * F_IN + lane], X[src * F_IN + lane] * ew[e]);
    }
}
__global__ __launch_bounds__(128) void gcn_proj_fb(const float* __restrict__ A,
                                                   const float* __restrict__ W,
                                                   const float* __restrict__ bias,
                                                   float* __restrict__ out) {
    __shared__ float arow[F_IN];
    const int n = blockIdx.x, f = threadIdx.x;
    if (f < F_IN) arow[f] = A[n * F_IN + f];
    __syncthreads();
    float acc = bias[f];
    #pragma unroll
    for (int k = 0; k < F_IN; ++k) acc = fmaf(arow[k], W[k * F_OUT + f], acc);
    out[n * F_OUT + f] = fmaxf(acc, 0.0f);
}

extern "C" void kernel_launch(void* const* d_in, const int* in_sizes, int n_in,
                              void* d_out, int out_size, void* d_ws, size_t ws_size,
                              hipStream_t stream) {
    const float* X    = (const float*)d_in[0];
    const int*   ei   = (const int*)  d_in[1];
    const float* ew   = (const float*)d_in[2];
    const float* W    = (const float*)d_in[3];
    const float* bias = (const float*)d_in[4];
    float*       out  = (float*)d_out;

    const size_t pack4_bytes = (size_t)NBKT * CAP2 * 4;                    // 14.8 MB
    const size_t xh_bytes    = (size_t)N_NODES * F_IN * 2;                 // 12.8 MB
    const size_t ah_bytes    = (size_t)N_NODES * F_IN * 2;                 // 12.8 MB
    const size_t nbase_bytes = (size_t)N_NODES * 4;
    const size_t ndeg_bytes  = (size_t)N_NODES * 4;
    const size_t dloc_bytes  = (size_t)NBKT * CAP2;                        // 3.7 MB
    const size_t bcnt_bytes  = (size_t)NBKT * 4;
    const size_t need = pack4_bytes + xh_bytes + ah_bytes + nbase_bytes +
                        ndeg_bytes + dloc_bytes + bcnt_bytes;

    if (ws_size >= need) {
        char* p = (char*)d_ws;
        unsigned*       pack4 = (unsigned*)p;       p += pack4_bytes;
        unsigned short* Xh    = (unsigned short*)p; p += xh_bytes;
        unsigned short* Ah    = (unsigned short*)p; p += ah_bytes;
        unsigned*       nbase = (unsigned*)p;       p += nbase_bytes;
        unsigned*       ndeg  = (unsigned*)p;       p += ndeg_bytes;
        unsigned char*  dloc8 = (unsigned char*)p;  p += dloc_bytes;
        unsigned*       bcur  = (unsigned*)p;       p += bcnt_bytes;

        hipMemsetAsync(bcur, 0, bcnt_bytes, stream);
        k_part<<<PART_BLOCKS, PART_THREADS, 0, stream>>>(X, Xh, ei, ew, bcur, pack4, dloc8);
        k_sort<<<NBKT, SORT_THREADS, 0, stream>>>(pack4, dloc8, bcur, nbase, ndeg);
        k_gather<<<N_NODES / 4, 256, 0, stream>>>(Xh, pack4, nbase, ndeg, Ah);
        k_proj<<<N_NODES / 16, 256, 0, stream>>>(Ah, W, bias, out);
    } else {
        float* A = (float*)d_ws;   // 25.6 MB
        hipMemsetAsync(A, 0, (size_t)N_NODES * F_IN * sizeof(float), stream);
        gcn_scatter_fb<<<4096, 256, 0, stream>>>(X, ei, ew, A);
        gcn_proj_fb<<<N_NODES, 128, 0, stream>>>(A, W, bias, out);
    }
}